// Round 15
// baseline (86.888 us; speedup 1.0000x reference)
//
#include <hip/hip_runtime.h>
#include <hip/hip_bf16.h>

#define BB 8
#define NN 512
#define DINC 128
#define DOUTC 128
#define HHC 8
#define EEC 16
#define DHC 16

typedef _Float16 h4 __attribute__((ext_vector_type(4)));
typedef float f32x4 __attribute__((ext_vector_type(4)));

__device__ __forceinline__ float wsum(float v){
#pragma unroll
  for (int o=1;o<64;o<<=1) v += __shfl_xor(v,o);
  return v;
}

// ---------- proj v2 (R11-verified): LN1 + MFMA GEMMs ----------
__global__ __launch_bounds__(256) void k_proj(
    const float* __restrict__ x,
    const float* __restrict__ g1, const float* __restrict__ b1,
    const float* __restrict__ Wp, const float* __restrict__ bp,
    const float* __restrict__ Wq, const float* __restrict__ Wk, const float* __restrict__ Wv,
    float* __restrict__ xp, _Float16* __restrict__ Qh, _Float16* __restrict__ Kh, _Float16* __restrict__ Vh)
{
  __shared__ _Float16 xln[16][136];
  __shared__ _Float16 xps[16][136];
  __shared__ float    xp32[16][132];
  __shared__ _Float16 qs[3][16][136];
  int tid=threadIdx.x, w=tid>>6, lane=tid&63;
  int c=lane&15, g=lane>>4;
  int row0 = blockIdx.x*16;
  int b = row0>>9, n0 = row0&(NN-1);

  float ga=g1[lane], gb=g1[lane+64], ba=b1[lane], bbx=b1[lane+64];
#pragma unroll
  for (int rr=0;rr<4;++rr){
    int r = w + rr*4;
    size_t gi = (size_t)(row0+r)*DINC + lane;
    float a = x[gi], cc = x[gi+64];
    float s = wsum(a+cc);
    float q = wsum(a*a+cc*cc);
    float mean = s*(1.f/DINC);
    float var  = q*(1.f/DINC)-mean*mean;
    float rstd = rsqrtf(var+1e-5f);
    xln[r][lane]    = (_Float16)((a -mean)*rstd*ga + ba);
    xln[r][lane+64] = (_Float16)((cc-mean)*rstd*gb + bbx);
  }
  __syncthreads();

#pragma unroll
  for (int oo=0;oo<2;++oo){
    int ot = 2*w+oo;
    float4 bi = *(const float4*)(bp + 16*ot + 4*g);
    f32x4 D; D[0]=bi.x; D[1]=bi.y; D[2]=bi.z; D[3]=bi.w;
#pragma unroll
    for (int kt=0;kt<8;++kt){
      h4 f;
#pragma unroll
      for (int j=0;j<4;++j)
        f[j] = (_Float16)Wp[(size_t)(16*kt+4*g+j)*DOUTC + 16*ot + c];
      h4 hb = *(const h4*)&xln[c][16*kt+4*g];
      D = __builtin_amdgcn_mfma_f32_16x16x16f16(f, hb, D, 0,0,0);
    }
#pragma unroll
    for (int r=0;r<4;++r){
      xp32[c][16*ot+4*g+r] = D[r];
      xps [c][16*ot+4*g+r] = (_Float16)D[r];
    }
  }
  __syncthreads();

#pragma unroll
  for (int pp=0;pp<6;++pp){
    int p = w + pp*4;
    int mat = p>>3, ot = p&7;
    const float* W = (mat==0)? Wq : ((mat==1)? Wk : Wv);
    f32x4 D = {0.f,0.f,0.f,0.f};
#pragma unroll
    for (int kt=0;kt<8;++kt){
      h4 f;
#pragma unroll
      for (int j=0;j<4;++j)
        f[j] = (_Float16)W[(size_t)(16*kt+4*g+j)*DOUTC + 16*ot + c];
      h4 hb = *(const h4*)&xps[c][16*kt+4*g];
      D = __builtin_amdgcn_mfma_f32_16x16x16f16(f, hb, D, 0,0,0);
    }
#pragma unroll
    for (int r=0;r<4;++r)
      qs[mat][c][16*ot+4*g+r] = (_Float16)D[r];
  }
  __syncthreads();

#pragma unroll
  for (int i=tid;i<512;i+=256){
    int r=i>>5, seg=i&31;
    *(float4*)(xp + (size_t)(row0+r)*DOUTC + seg*4) = *(const float4*)&xp32[r][seg*4];
  }
#pragma unroll
  for (int mat=0;mat<3;++mat){
    int r = tid>>4, seg = tid&15;
    int h = seg>>1, d = (seg&1)*8;
    _Float16* O = (mat==0)? Qh : ((mat==1)? Kh : Vh);
    *(float4*)(O + (((size_t)b*HHC+h)*NN + n0+r)*DHC + d) = *(const float4*)&qs[mat][r][seg*8];
  }
}

// ---------- edge-bias MLP v6: stream-dense / compute-sparse ----------
// Per (b,n) row, per 256-edge half: stage ea COALESCED into LDS (stride 80B,
// ~2-way banks), compact indices, run the R10/R11-verified MLP with gathers
// redirected to LDS. Fixes the scattered-16B global gather (~1 TB/s ceiling,
// R13 counters) by moving scatter into LDS and keeping HBM/L3 reads streaming.
__global__ __launch_bounds__(256) void k_edge(
  const float* __restrict__ ea, const int* __restrict__ adj,
  const float* __restrict__ eg, const float* __restrict__ ebi,
  const float* __restrict__ We1, const float* __restrict__ be1,
  const float* __restrict__ We2, const float* __restrict__ be2,
  _Float16* __restrict__ ebias)
{
  __shared__ float eaL[256*20];              // 20KB: 256 edges x 16f @ stride 20
  __shared__ _Float16 stage[8][520];         // 8.3KB
  __shared__ unsigned long long msk[8];
  __shared__ unsigned short idx16[256];      // per-half local indices

  int tid = threadIdx.x, w = tid>>6, lane = tid&63;
  int c = lane&15, g = lane>>4;
  int bn = blockIdx.x;
  int b = bn >> 9, n = bn & (NN-1);

  // adjacency ballots for all 8 chunks (+ self loop)
  const int* adjRow = adj + (size_t)bn*NN;
  int col1 = tid, col2 = tid + 256;
  int v1 = (adjRow[col1] != 0) || (col1 == n);
  int v2 = (adjRow[col2] != 0) || (col2 == n);
  unsigned long long b1m = __ballot(v1);
  unsigned long long b2m = __ballot(v2);
  if (lane==0){ msk[w] = b1m; msk[4+w] = b2m; }

  // MLP weight A-fragments (transposed-layer trick, R3+-verified)
  h4 w1a,w1b,w2a,w2b;
#pragma unroll
  for (int j=0;j<4;++j){
    w1a[j] = (_Float16)We1[(4*g+j)*32 + c];
    w1b[j] = (_Float16)We1[(4*g+j)*32 + 16 + c];
    w2a[j] = (_Float16)((c<8)? We2[(4*g+j)*HHC + c] : 0.f);
    w2b[j] = (_Float16)((c<8)? We2[(16+4*g+j)*HHC + c] : 0.f);
  }
  float4 b1a = *(const float4*)(be1 + 4*g);
  float4 b1b = *(const float4*)(be1 + 16 + 4*g);
  float4 b2r = *(const float4*)(be2 + (g&1)*4);
  float4 G4  = *(const float4*)(eg  + 4*g);
  float4 Bv4 = *(const float4*)(ebi + 4*g);

  // prefill stage with -30000 (masked default)
  {
    _Float16 neg = (_Float16)(-30000.f);
    h4 negv; negv[0]=neg; negv[1]=neg; negv[2]=neg; negv[3]=neg;
#pragma unroll
    for (int i=tid;i<1024;i+=256){
      int h = i>>7, m4 = i&127;
      *(h4*)&stage[h][m4*4] = negv;
    }
  }
  __syncthreads();                 // msk visible (prefill completes before half-0 barrier anyway)

  const float* eaRow = ea + (size_t)bn*NN*EEC;

#pragma unroll
  for (int half=0; half<2; ++half){
    // ---- stage this half's ea into LDS: coalesced float4 streaming
#pragma unroll
    for (int it=0; it<4; ++it){
      int i = tid + it*256;                 // 0..1023
      int e = i>>2, part = i&3;
      float4 v = *(const float4*)(eaRow + (size_t)(half*256 + e)*EEC + part*4);
      *(float4*)&eaL[e*20 + part*4] = v;
    }
    // ---- per-half compaction (local indices 0..255)
    int offs[4]; int cnt = 0;
#pragma unroll
    for (int k=0;k<4;++k){ offs[k] = cnt; cnt += __popcll(msk[4*half + k]); }
    unsigned long long bits = msk[4*half + w];
    if ((bits >> lane) & 1ull){
      int pos = offs[w] + __popcll(bits & ((1ull<<lane)-1ull));
      idx16[pos] = (unsigned short)(w*64 + lane);
    }
    __syncthreads();               // eaL + idx16 ready

    if (cnt > 0){
      int nt = (cnt + 15) >> 4;
      for (int t = w; t < nt; t += 4){
        int slot = 16*t + c;
        int sidx = slot < cnt ? slot : cnt-1;
        int lidx = idx16[sidx];
        float4 v = *(const float4*)&eaL[lidx*20 + 4*g];   // LDS gather (~2-way banks)
        float s = v.x+v.y+v.z+v.w;
        float q = v.x*v.x+v.y*v.y+v.z*v.z+v.w*v.w;
        s += __shfl_xor(s,16); s += __shfl_xor(s,32);
        q += __shfl_xor(q,16); q += __shfl_xor(q,32);
        float mean = s*(1.f/EEC);
        float var  = q*(1.f/EEC) - mean*mean;
        float rstd = rsqrtf(var + 1e-5f);
        h4 ef;
        ef[0]=(_Float16)((v.x-mean)*rstd*G4.x + Bv4.x);
        ef[1]=(_Float16)((v.y-mean)*rstd*G4.y + Bv4.y);
        ef[2]=(_Float16)((v.z-mean)*rstd*G4.z + Bv4.z);
        ef[3]=(_Float16)((v.w-mean)*rstd*G4.w + Bv4.w);
        f32x4 d1a = {b1a.x,b1a.y,b1a.z,b1a.w};
        f32x4 d1b = {b1b.x,b1b.y,b1b.z,b1b.w};
        d1a = __builtin_amdgcn_mfma_f32_16x16x16f16(w1a, ef, d1a, 0,0,0);
        d1b = __builtin_amdgcn_mfma_f32_16x16x16f16(w1b, ef, d1b, 0,0,0);
        h4 hfa,hfb;
#pragma unroll
        for (int r=0;r<4;++r){
          hfa[r]=(_Float16)fmaxf(d1a[r],0.f);
          hfb[r]=(_Float16)fmaxf(d1b[r],0.f);
        }
        f32x4 d2 = {0.f,0.f,0.f,0.f};
        d2 = __builtin_amdgcn_mfma_f32_16x16x16f16(w2a, hfa, d2, 0,0,0);
        d2 = __builtin_amdgcn_mfma_f32_16x16x16f16(w2b, hfb, d2, 0,0,0);
        if (g<2 && slot<cnt){
          int gcol = half*256 + lidx;
#pragma unroll
          for (int r=0;r<4;++r){
            float y = d2[r] + ((const float*)&b2r)[r];
            y = fminf(fmaxf(2.f*y,-30.f),30.f);
            float ex = __expf(y);
            float t2 = (ex-1.f)/(ex+1.f);          // tanh
            stage[4*g+r][gcol] = (_Float16)(5.f*t2);
          }
        }
      }
    }
    __syncthreads();               // MLP done before next half's staging overwrites eaL/idx16
  }

  // ---- coalesced writeout: 8 head planes x 1KB
  size_t base = ((size_t)b*HHC)*NN*NN + (size_t)n*NN;
#pragma unroll
  for (int i=tid;i<512;i+=256){
    int h = i>>6, m8 = i&63;
    *(float4*)(ebias + base + (size_t)h*NN*NN + m8*8) =
        *(const float4*)&stage[h][m8*8];
  }
}

// ---------- MFMA attention (R9-R14-verified, unchanged) ----------
__global__ __launch_bounds__(256) void k_attn(
  const _Float16* __restrict__ Qh, const _Float16* __restrict__ Kh, const _Float16* __restrict__ Vh,
  const _Float16* __restrict__ eb, float* __restrict__ ctxb)
{
  __shared__ _Float16 Klds[NN*DHC];
  __shared__ _Float16 Vt[DHC*520];
  int tid = threadIdx.x;
  int bh   = blockIdx.x >> 3;
  int tile = blockIdx.x & 7;
  const _Float16* Kg = Kh + (size_t)bh*NN*DHC;
  const _Float16* Vg = Vh + (size_t)bh*NN*DHC;
  {
    const float4* src = (const float4*)Kg;
    float4* dst = (float4*)Klds;
#pragma unroll
    for (int i=tid;i<1024;i+=256) dst[i]=src[i];
  }
  {
#pragma unroll
    for (int i=tid;i<1024;i+=256){
      int m = i>>1, hf = i&1;
      float4 v4 = *(const float4*)(Vg + (size_t)m*DHC + hf*8);
      const _Float16* hh = (const _Float16*)&v4;
#pragma unroll
      for (int jj=0;jj<8;++jj) Vt[(hf*8+jj)*520 + m] = hh[jj];
    }
  }
  __syncthreads();

  int w = tid>>6, lane = tid&63;
  int c = lane&15, g = lane>>4;
  int n0 = tile*64 + w*16;

  h4 qf = *(const h4*)(Qh + ((size_t)bh*NN + n0 + c)*DHC + 4*g);
  const _Float16* ebw = eb + ((size_t)bh*NN + n0 + c)*NN + 4*g;

  f32x4 zero = {0.f,0.f,0.f,0.f};
  f32x4 acc = zero;
  float rowsum = 0.f;
#pragma unroll
  for (int t=0;t<32;++t){
    h4 kf = *(const h4*)(Klds + (16*t + c)*DHC + 4*g);
    f32x4 d = __builtin_amdgcn_mfma_f32_16x16x16f16(kf, qf, zero, 0, 0, 0);
    h4 e4 = *(const h4*)(ebw + 16*t);
    h4 pa;
#pragma unroll
    for (int r=0;r<4;++r){
      float sv = d[r]*0.25f + (float)e4[r];
      sv = fmaxf(sv,0.f) + 0.2f*fminf(sv,0.f);
      float p = __expf(sv - 6.f);
      rowsum += p;
      pa[r] = (_Float16)p;
    }
    h4 vf = *(const h4*)(Vt + c*520 + 16*t + 4*g);
    acc = __builtin_amdgcn_mfma_f32_16x16x16f16(pa, vf, acc, 0, 0, 0);
  }
  rowsum += __shfl_xor(rowsum,16);
  rowsum += __shfl_xor(rowsum,32);

  int b = bh>>3, h = bh&7;
#pragma unroll
  for (int r=0;r<4;++r){
    float sr = __shfl(rowsum, g*16 + 4*g + r);
    ctxb[((size_t)b*NN + n0 + 4*g + r)*DOUTC + h*DHC + c] = acc[r]/sr;
  }
}

// ---------- FFN v4 (R11-verified, f32 xp, unchanged) ----------
__global__ __launch_bounds__(256) void k_ffn(
  const float* __restrict__ xp, const float* __restrict__ ctxb,
  const float* __restrict__ g2, const float* __restrict__ b2v,
  const float* __restrict__ W1, const float* __restrict__ bb1,
  const float* __restrict__ W2, const float* __restrict__ bb2,
  float* __restrict__ out)
{
  __shared__ float    hrow[8][DOUTC];
  __shared__ _Float16 hn[16][136];
  __shared__ float    part[4][8][16][16];

  int tid = threadIdx.x, w = tid>>6, lane = tid&63;
  int c = lane&15, g = lane>>4;
  int n0 = blockIdx.x * 8;

#pragma unroll
  for (int i=tid;i<272;i+=256){
    h4 z = {(_Float16)0.f,(_Float16)0.f,(_Float16)0.f,(_Float16)0.f};
    ((h4*)hn)[272+i] = z;
  }

  float ga=g2[lane], gb=g2[lane+64], ba=b2v[lane], bbx=b2v[lane+64];
#pragma unroll
  for (int rr=0;rr<2;++rr){
    int r = w + rr*4;
    size_t gi = (size_t)(n0+r)*DOUTC + lane;
    float a  = xp[gi]    + ctxb[gi];
    float cc = xp[gi+64] + ctxb[gi+64];
    hrow[r][lane] = a; hrow[r][lane+64] = cc;
    float s = wsum(a+cc);
    float q = wsum(a*a+cc*cc);
    float mean = s*(1.f/DOUTC);
    float var  = q*(1.f/DOUTC) - mean*mean;
    float rstd = rsqrtf(var + 1e-5f);
    hn[r][lane]    = (_Float16)((a -mean)*rstd*ga + ba);
    hn[r][lane+64] = (_Float16)((cc-mean)*rstd*gb + bbx);
  }
  __syncthreads();

  h4 hidB[4];
#pragma unroll
  for (int t=0;t<4;++t){
    int ht = 4*w + t;
    float4 bi = *(const float4*)(bb1 + 16*ht + 4*g);
    f32x4 D1; D1[0]=bi.x; D1[1]=bi.y; D1[2]=bi.z; D1[3]=bi.w;
#pragma unroll
    for (int kt=0;kt<8;++kt){
      h4 f;
#pragma unroll
      for (int j=0;j<4;++j)
        f[j] = (_Float16)W1[(size_t)(16*kt + 4*g + j)*256 + 16*ht + c];
      h4 hb = *(const h4*)&hn[c][16*kt + 4*g];
      D1 = __builtin_amdgcn_mfma_f32_16x16x16f16(f, hb, D1, 0,0,0);
    }
#pragma unroll
    for (int r=0;r<4;++r) hidB[t][r] = (_Float16)fmaxf(D1[r], 0.f);
  }

#pragma unroll
  for (int ot=0;ot<8;++ot){
    f32x4 d2 = {0.f,0.f,0.f,0.f};
#pragma unroll
    for (int t=0;t<4;++t){
      h4 f;
#pragma unroll
      for (int j=0;j<4;++j)
        f[j] = (_Float16)W2[(size_t)(16*(4*w+t) + 4*g + j)*128 + 16*ot + c];
      d2 = __builtin_amdgcn_mfma_f32_16x16x16f16(f, hidB[t], d2, 0,0,0);
    }
#pragma unroll
    for (int r=0;r<4;++r) part[w][ot][4*g+r][c] = d2[r];
  }
  __syncthreads();

#pragma unroll
  for (int i=tid;i<1024;i+=256){
    int n = i>>7, col = i&127;
    int ot = col>>4, m = col&15;
    float v = part[0][ot][m][n] + part[1][ot][m][n]
            + part[2][ot][m][n] + part[3][ot][m][n];
    out[(size_t)(n0+n)*DOUTC + col] = hrow[n][col] + v + bb2[col];
  }
}

extern "C" void kernel_launch(void* const* d_in, const int* in_sizes, int n_in,
                              void* d_out, int out_size, void* d_ws, size_t ws_size,
                              hipStream_t stream)
{
  const float* x     = (const float*)d_in[0];
  const int*   adj   = (const int*)  d_in[1];
  const float* ea    = (const float*)d_in[2];
  const float* ln1_g = (const float*)d_in[3];
  const float* ln1_b = (const float*)d_in[4];
  const float* Wp    = (const float*)d_in[5];
  const float* bp    = (const float*)d_in[6];
  const float* eln_g = (const float*)d_in[7];
  const float* eln_b = (const float*)d_in[8];
  const float* We1   = (const float*)d_in[9];
  const float* be1   = (const float*)d_in[10];
  const float* We2   = (const float*)d_in[11];
  const float* be2   = (const float*)d_in[12];
  const float* Wq    = (const float*)d_in[13];
  const float* Wk    = (const float*)d_in[14];
  const float* Wv    = (const float*)d_in[15];
  const float* ffW1  = (const float*)d_in[16];
  const float* ffb1  = (const float*)d_in[17];
  const float* ffW2  = (const float*)d_in[18];
  const float* ffb2  = (const float*)d_in[19];
  const float* ln2_g = (const float*)d_in[20];
  const float* ln2_b = (const float*)d_in[21];
  float* out = (float*)d_out;

  char* ws = (char*)d_ws;
  float*    xp  = (float*)(ws);                       // 2MB (f32)
  float*    ctx = (float*)(ws + ((size_t)2<<20));     // 2MB
  _Float16* Qh  = (_Float16*)(ws + ((size_t)4<<20));  // 1MB
  _Float16* Kh  = (_Float16*)(ws + ((size_t)5<<20));  // 1MB
  _Float16* Vh  = (_Float16*)(ws + ((size_t)6<<20));  // 1MB
  _Float16* ebf = (_Float16*)(ws + ((size_t)7<<20));  // 32MB [B,H,N,N] f16 (mask baked)

  k_proj<<<(BB*NN)/16, 256, 0, stream>>>(x, ln1_g, ln1_b, Wp, bp, Wq, Wk, Wv, xp, Qh, Kh, Vh);
  k_edge<<<BB*NN, 256, 0, stream>>>(ea, adj, eln_g, eln_b, We1, be1, We2, be2, ebf);
  k_attn<<<BB*HHC*8, 256, 0, stream>>>(Qh, Kh, Vh, ebf, ctx);
  k_ffn<<<(BB*NN)/8, 256, 0, stream>>>(xp, ctx, ln2_g, ln2_b, ffW1, ffb1, ffW2, ffb2, out);
}

// Round 16
// 79.913 us; speedup vs baseline: 1.0873x; 1.0873x over previous
//
#include <hip/hip_runtime.h>
#include <hip/hip_bf16.h>

#define BB 8
#define NN 512
#define DINC 128
#define DOUTC 128
#define HHC 8
#define EEC 16
#define DHC 16

typedef _Float16 h4 __attribute__((ext_vector_type(4)));
typedef float f32x4 __attribute__((ext_vector_type(4)));

__device__ __forceinline__ float wsum(float v){
#pragma unroll
  for (int o=1;o<64;o<<=1) v += __shfl_xor(v,o);
  return v;
}

// ---------- proj v2 (R11-verified): LN1 + MFMA GEMMs ----------
__global__ __launch_bounds__(256) void k_proj(
    const float* __restrict__ x,
    const float* __restrict__ g1, const float* __restrict__ b1,
    const float* __restrict__ Wp, const float* __restrict__ bp,
    const float* __restrict__ Wq, const float* __restrict__ Wk, const float* __restrict__ Wv,
    float* __restrict__ xp, _Float16* __restrict__ Qh, _Float16* __restrict__ Kh, _Float16* __restrict__ Vh)
{
  __shared__ _Float16 xln[16][136];
  __shared__ _Float16 xps[16][136];
  __shared__ float    xp32[16][132];
  __shared__ _Float16 qs[3][16][136];
  int tid=threadIdx.x, w=tid>>6, lane=tid&63;
  int c=lane&15, g=lane>>4;
  int row0 = blockIdx.x*16;
  int b = row0>>9, n0 = row0&(NN-1);

  float ga=g1[lane], gb=g1[lane+64], ba=b1[lane], bbx=b1[lane+64];
#pragma unroll
  for (int rr=0;rr<4;++rr){
    int r = w + rr*4;
    size_t gi = (size_t)(row0+r)*DINC + lane;
    float a = x[gi], cc = x[gi+64];
    float s = wsum(a+cc);
    float q = wsum(a*a+cc*cc);
    float mean = s*(1.f/DINC);
    float var  = q*(1.f/DINC)-mean*mean;
    float rstd = rsqrtf(var+1e-5f);
    xln[r][lane]    = (_Float16)((a -mean)*rstd*ga + ba);
    xln[r][lane+64] = (_Float16)((cc-mean)*rstd*gb + bbx);
  }
  __syncthreads();

#pragma unroll
  for (int oo=0;oo<2;++oo){
    int ot = 2*w+oo;
    float4 bi = *(const float4*)(bp + 16*ot + 4*g);
    f32x4 D; D[0]=bi.x; D[1]=bi.y; D[2]=bi.z; D[3]=bi.w;
#pragma unroll
    for (int kt=0;kt<8;++kt){
      h4 f;
#pragma unroll
      for (int j=0;j<4;++j)
        f[j] = (_Float16)Wp[(size_t)(16*kt+4*g+j)*DOUTC + 16*ot + c];
      h4 hb = *(const h4*)&xln[c][16*kt+4*g];
      D = __builtin_amdgcn_mfma_f32_16x16x16f16(f, hb, D, 0,0,0);
    }
#pragma unroll
    for (int r=0;r<4;++r){
      xp32[c][16*ot+4*g+r] = D[r];
      xps [c][16*ot+4*g+r] = (_Float16)D[r];
    }
  }
  __syncthreads();

#pragma unroll
  for (int pp=0;pp<6;++pp){
    int p = w + pp*4;
    int mat = p>>3, ot = p&7;
    const float* W = (mat==0)? Wq : ((mat==1)? Wk : Wv);
    f32x4 D = {0.f,0.f,0.f,0.f};
#pragma unroll
    for (int kt=0;kt<8;++kt){
      h4 f;
#pragma unroll
      for (int j=0;j<4;++j)
        f[j] = (_Float16)W[(size_t)(16*kt+4*g+j)*DOUTC + 16*ot + c];
      h4 hb = *(const h4*)&xps[c][16*kt+4*g];
      D = __builtin_amdgcn_mfma_f32_16x16x16f16(f, hb, D, 0,0,0);
    }
#pragma unroll
    for (int r=0;r<4;++r)
      qs[mat][c][16*ot+4*g+r] = (_Float16)D[r];
  }
  __syncthreads();

#pragma unroll
  for (int i=tid;i<512;i+=256){
    int r=i>>5, seg=i&31;
    *(float4*)(xp + (size_t)(row0+r)*DOUTC + seg*4) = *(const float4*)&xp32[r][seg*4];
  }
#pragma unroll
  for (int mat=0;mat<3;++mat){
    int r = tid>>4, seg = tid&15;
    int h = seg>>1, d = (seg&1)*8;
    _Float16* O = (mat==0)? Qh : ((mat==1)? Kh : Vh);
    *(float4*)(O + (((size_t)b*HHC+h)*NN + n0+r)*DHC + d) = *(const float4*)&qs[mat][r][seg*8];
  }
}

// ---------- edge-bias MLP v7: R10/R11 compaction + instruction diet ----------
// Issue-bound (R8/R14/R15 nulls + R13 counters: no pipe >30%): cut instructions,
// not data movement. __fdividef in tanh (~8 fewer instr/output), 16B prefill.
__global__ __launch_bounds__(256) void k_edge(
  const float* __restrict__ ea, const int* __restrict__ adj,
  const float* __restrict__ eg, const float* __restrict__ ebi,
  const float* __restrict__ We1, const float* __restrict__ be1,
  const float* __restrict__ We2, const float* __restrict__ be2,
  _Float16* __restrict__ ebias)
{
  __shared__ _Float16 stage[8][520];
  __shared__ unsigned long long msk[8];
  __shared__ unsigned short idx16[512];
  __shared__ int cntS;

  int tid = threadIdx.x, w = tid>>6, lane = tid&63;
  int c = lane&15, g = lane>>4;
  int bn = blockIdx.x;
  int b = bn >> 9, n = bn & (NN-1);

  const int* adjRow = adj + (size_t)bn*NN;
  int col1 = tid, col2 = tid + 256;
  int v1 = (adjRow[col1] != 0) || (col1 == n);
  int v2 = (adjRow[col2] != 0) || (col2 == n);
  unsigned long long b1m = __ballot(v1);
  unsigned long long b2m = __ballot(v2);
  if (lane==0){ msk[w] = b1m; msk[4+w] = b2m; }

  h4 w1a,w1b,w2a,w2b;
#pragma unroll
  for (int j=0;j<4;++j){
    w1a[j] = (_Float16)We1[(4*g+j)*32 + c];
    w1b[j] = (_Float16)We1[(4*g+j)*32 + 16 + c];
    w2a[j] = (_Float16)((c<8)? We2[(4*g+j)*HHC + c] : 0.f);
    w2b[j] = (_Float16)((c<8)? We2[(16+4*g+j)*HHC + c] : 0.f);
  }
  float4 b1a = *(const float4*)(be1 + 4*g);
  float4 b1b = *(const float4*)(be1 + 16 + 4*g);
  float4 b2r = *(const float4*)(be2 + (g&1)*4);
  float4 G4  = *(const float4*)(eg  + 4*g);
  float4 Bv4 = *(const float4*)(ebi + 4*g);

  __syncthreads();

  int offs[8]; int cnt = 0;
#pragma unroll
  for (int k=0;k<8;++k){ offs[k] = cnt; cnt += __popcll(msk[k]); }
  if (tid==0) cntS = cnt;

  { // prefill stage with -30000, 16B writes ([8][520]: row stride 1040B, 16B-divisible)
    _Float16 neg = (_Float16)(-30000.f);
    _Float16 nv8[8] = {neg,neg,neg,neg,neg,neg,neg,neg};
    float4 negv = *(const float4*)nv8;
#pragma unroll
    for (int i=tid;i<512;i+=256){
      int h = i>>6, m8 = i&63;
      *(float4*)&stage[h][m8*8] = negv;
    }
  }

  if (v1){
    int pos = offs[w]   + __popcll(msk[w]   & ((1ull<<lane)-1ull));
    idx16[pos] = (unsigned short)col1;
  }
  if (v2){
    int pos = offs[4+w] + __popcll(msk[4+w] & ((1ull<<lane)-1ull));
    idx16[pos] = (unsigned short)col2;
  }
  __syncthreads();

  cnt = cntS;
  int nt = (cnt + 15) >> 4;
  const float* eaRow = ea + (size_t)bn*NN*EEC;

  for (int t = w; t < nt; t += 4){
    int slot = 16*t + c;
    int sidx = slot < cnt ? slot : cnt-1;
    int idx  = idx16[sidx];
    float4 v = *(const float4*)(eaRow + (size_t)idx*EEC + 4*g);
    float s = v.x+v.y+v.z+v.w;
    float q = v.x*v.x+v.y*v.y+v.z*v.z+v.w*v.w;
    s += __shfl_xor(s,16); s += __shfl_xor(s,32);
    q += __shfl_xor(q,16); q += __shfl_xor(q,32);
    float mean = s*(1.f/EEC);
    float var  = q*(1.f/EEC) - mean*mean;
    float rstd = rsqrtf(var + 1e-5f);
    h4 ef;
    ef[0]=(_Float16)((v.x-mean)*rstd*G4.x + Bv4.x);
    ef[1]=(_Float16)((v.y-mean)*rstd*G4.y + Bv4.y);
    ef[2]=(_Float16)((v.z-mean)*rstd*G4.z + Bv4.z);
    ef[3]=(_Float16)((v.w-mean)*rstd*G4.w + Bv4.w);
    f32x4 d1a = {b1a.x,b1a.y,b1a.z,b1a.w};
    f32x4 d1b = {b1b.x,b1b.y,b1b.z,b1b.w};
    d1a = __builtin_amdgcn_mfma_f32_16x16x16f16(w1a, ef, d1a, 0,0,0);
    d1b = __builtin_amdgcn_mfma_f32_16x16x16f16(w1b, ef, d1b, 0,0,0);
    h4 hfa,hfb;
#pragma unroll
    for (int r=0;r<4;++r){
      hfa[r]=(_Float16)fmaxf(d1a[r],0.f);
      hfb[r]=(_Float16)fmaxf(d1b[r],0.f);
    }
    f32x4 d2 = {0.f,0.f,0.f,0.f};
    d2 = __builtin_amdgcn_mfma_f32_16x16x16f16(w2a, hfa, d2, 0,0,0);
    d2 = __builtin_amdgcn_mfma_f32_16x16x16f16(w2b, hfb, d2, 0,0,0);
    if (g<2 && slot<cnt){
#pragma unroll
      for (int r=0;r<4;++r){
        float y = d2[r] + ((const float*)&b2r)[r];
        y = fminf(fmaxf(2.f*y,-30.f),30.f);
        float ex = __expf(y);
        float t2 = __fdividef(ex-1.f, ex+1.f);   // fast tanh ratio (abs err ~1e-6)
        stage[4*g+r][idx] = (_Float16)(5.f*t2);
      }
    }
  }
  __syncthreads();

  size_t base = ((size_t)b*HHC)*NN*NN + (size_t)n*NN;
#pragma unroll
  for (int i=tid;i<512;i+=256){
    int h = i>>6, m8 = i&63;
    *(float4*)(ebias + base + (size_t)h*NN*NN + m8*8) =
        *(const float4*)&stage[h][m8*8];
  }
}

// ---------- MFMA attention v3: K direct from L2, V-only LDS (occupancy 2->8 blk/CU) ----------
__global__ __launch_bounds__(256) void k_attn(
  const _Float16* __restrict__ Qh, const _Float16* __restrict__ Kh, const _Float16* __restrict__ Vh,
  const _Float16* __restrict__ eb, float* __restrict__ ctxb)
{
  __shared__ _Float16 Vt[DHC*520];       // 16.25KB only
  int tid = threadIdx.x;
  int bh   = blockIdx.x >> 3;
  int tile = blockIdx.x & 7;
  const _Float16* Vg = Vh + (size_t)bh*NN*DHC;
  {
#pragma unroll
    for (int i=tid;i<1024;i+=256){
      int m = i>>1, hf = i&1;
      float4 v4 = *(const float4*)(Vg + (size_t)m*DHC + hf*8);
      const _Float16* hh = (const _Float16*)&v4;
#pragma unroll
      for (int jj=0;jj<8;++jj) Vt[(hf*8+jj)*520 + m] = hh[jj];
    }
  }
  __syncthreads();

  int w = tid>>6, lane = tid&63;
  int c = lane&15, g = lane>>4;
  int n0 = tile*64 + w*16;

  h4 qf = *(const h4*)(Qh + ((size_t)bh*NN + n0 + c)*DHC + 4*g);
  const _Float16* ebw = eb + ((size_t)bh*NN + n0 + c)*NN + 4*g;
  const _Float16* Kb  = Kh + (size_t)bh*NN*DHC;

  f32x4 zero = {0.f,0.f,0.f,0.f};
  f32x4 acc = zero;
  float rowsum = 0.f;
#pragma unroll
  for (int t=0;t<32;++t){
    h4 kf = *(const h4*)(Kb + (size_t)(16*t + c)*DHC + 4*g);   // L2-resident, coalesced 512B/wave
    f32x4 d = __builtin_amdgcn_mfma_f32_16x16x16f16(kf, qf, zero, 0, 0, 0);
    h4 e4 = *(const h4*)(ebw + 16*t);
    h4 pa;
#pragma unroll
    for (int r=0;r<4;++r){
      float sv = d[r]*0.25f + (float)e4[r];
      sv = fmaxf(sv,0.f) + 0.2f*fminf(sv,0.f);
      float p = __expf(sv - 6.f);
      rowsum += p;
      pa[r] = (_Float16)p;
    }
    h4 vf = *(const h4*)(Vt + c*520 + 16*t + 4*g);
    acc = __builtin_amdgcn_mfma_f32_16x16x16f16(pa, vf, acc, 0, 0, 0);
  }
  rowsum += __shfl_xor(rowsum,16);
  rowsum += __shfl_xor(rowsum,32);

  int b = bh>>3, h = bh&7;
#pragma unroll
  for (int r=0;r<4;++r){
    float sr = __shfl(rowsum, g*16 + 4*g + r);
    ctxb[((size_t)b*NN + n0 + 4*g + r)*DOUTC + h*DHC + c] = acc[r]/sr;
  }
}

// ---------- FFN v4 (R11-verified, f32 xp, unchanged) ----------
__global__ __launch_bounds__(256) void k_ffn(
  const float* __restrict__ xp, const float* __restrict__ ctxb,
  const float* __restrict__ g2, const float* __restrict__ b2v,
  const float* __restrict__ W1, const float* __restrict__ bb1,
  const float* __restrict__ W2, const float* __restrict__ bb2,
  float* __restrict__ out)
{
  __shared__ float    hrow[8][DOUTC];
  __shared__ _Float16 hn[16][136];
  __shared__ float    part[4][8][16][16];

  int tid = threadIdx.x, w = tid>>6, lane = tid&63;
  int c = lane&15, g = lane>>4;
  int n0 = blockIdx.x * 8;

#pragma unroll
  for (int i=tid;i<272;i+=256){
    h4 z = {(_Float16)0.f,(_Float16)0.f,(_Float16)0.f,(_Float16)0.f};
    ((h4*)hn)[272+i] = z;
  }

  float ga=g2[lane], gb=g2[lane+64], ba=b2v[lane], bbx=b2v[lane+64];
#pragma unroll
  for (int rr=0;rr<2;++rr){
    int r = w + rr*4;
    size_t gi = (size_t)(n0+r)*DOUTC + lane;
    float a  = xp[gi]    + ctxb[gi];
    float cc = xp[gi+64] + ctxb[gi+64];
    hrow[r][lane] = a; hrow[r][lane+64] = cc;
    float s = wsum(a+cc);
    float q = wsum(a*a+cc*cc);
    float mean = s*(1.f/DOUTC);
    float var  = q*(1.f/DOUTC) - mean*mean;
    float rstd = rsqrtf(var + 1e-5f);
    hn[r][lane]    = (_Float16)((a -mean)*rstd*ga + ba);
    hn[r][lane+64] = (_Float16)((cc-mean)*rstd*gb + bbx);
  }
  __syncthreads();

  h4 hidB[4];
#pragma unroll
  for (int t=0;t<4;++t){
    int ht = 4*w + t;
    float4 bi = *(const float4*)(bb1 + 16*ht + 4*g);
    f32x4 D1; D1[0]=bi.x; D1[1]=bi.y; D1[2]=bi.z; D1[3]=bi.w;
#pragma unroll
    for (int kt=0;kt<8;++kt){
      h4 f;
#pragma unroll
      for (int j=0;j<4;++j)
        f[j] = (_Float16)W1[(size_t)(16*kt + 4*g + j)*256 + 16*ht + c];
      h4 hb = *(const h4*)&hn[c][16*kt + 4*g];
      D1 = __builtin_amdgcn_mfma_f32_16x16x16f16(f, hb, D1, 0,0,0);
    }
#pragma unroll
    for (int r=0;r<4;++r) hidB[t][r] = (_Float16)fmaxf(D1[r], 0.f);
  }

#pragma unroll
  for (int ot=0;ot<8;++ot){
    f32x4 d2 = {0.f,0.f,0.f,0.f};
#pragma unroll
    for (int t=0;t<4;++t){
      h4 f;
#pragma unroll
      for (int j=0;j<4;++j)
        f[j] = (_Float16)W2[(size_t)(16*(4*w+t) + 4*g + j)*128 + 16*ot + c];
      d2 = __builtin_amdgcn_mfma_f32_16x16x16f16(f, hidB[t], d2, 0,0,0);
    }
#pragma unroll
    for (int r=0;r<4;++r) part[w][ot][4*g+r][c] = d2[r];
  }
  __syncthreads();

#pragma unroll
  for (int i=tid;i<1024;i+=256){
    int n = i>>7, col = i&127;
    int ot = col>>4, m = col&15;
    float v = part[0][ot][m][n] + part[1][ot][m][n]
            + part[2][ot][m][n] + part[3][ot][m][n];
    out[(size_t)(n0+n)*DOUTC + col] = hrow[n][col] + v + bb2[col];
  }
}

extern "C" void kernel_launch(void* const* d_in, const int* in_sizes, int n_in,
                              void* d_out, int out_size, void* d_ws, size_t ws_size,
                              hipStream_t stream)
{
  const float* x     = (const float*)d_in[0];
  const int*   adj   = (const int*)  d_in[1];
  const float* ea    = (const float*)d_in[2];
  const float* ln1_g = (const float*)d_in[3];
  const float* ln1_b = (const float*)d_in[4];
  const float* Wp    = (const float*)d_in[5];
  const float* bp    = (const float*)d_in[6];
  const float* eln_g = (const float*)d_in[7];
  const float* eln_b = (const float*)d_in[8];
  const float* We1   = (const float*)d_in[9];
  const float* be1   = (const float*)d_in[10];
  const float* We2   = (const float*)d_in[11];
  const float* be2   = (const float*)d_in[12];
  const float* Wq    = (const float*)d_in[13];
  const float* Wk    = (const float*)d_in[14];
  const float* Wv    = (const float*)d_in[15];
  const float* ffW1  = (const float*)d_in[16];
  const float* ffb1  = (const float*)d_in[17];
  const float* ffW2  = (const float*)d_in[18];
  const float* ffb2  = (const float*)d_in[19];
  const float* ln2_g = (const float*)d_in[20];
  const float* ln2_b = (const float*)d_in[21];
  float* out = (float*)d_out;

  char* ws = (char*)d_ws;
  float*    xp  = (float*)(ws);                       // 2MB (f32)
  float*    ctx = (float*)(ws + ((size_t)2<<20));     // 2MB
  _Float16* Qh  = (_Float16*)(ws + ((size_t)4<<20));  // 1MB
  _Float16* Kh  = (_Float16*)(ws + ((size_t)5<<20));  // 1MB
  _Float16* Vh  = (_Float16*)(ws + ((size_t)6<<20));  // 1MB
  _Float16* ebf = (_Float16*)(ws + ((size_t)7<<20));  // 32MB [B,H,N,N] f16 (mask baked)

  k_proj<<<(BB*NN)/16, 256, 0, stream>>>(x, ln1_g, ln1_b, Wp, bp, Wq, Wk, Wv, xp, Qh, Kh, Vh);
  k_edge<<<BB*NN, 256, 0, stream>>>(ea, adj, eln_g, eln_b, We1, be1, We2, be2, ebf);
  k_attn<<<BB*HHC*8, 256, 0, stream>>>(Qh, Kh, Vh, ebf, ctx);
  k_ffn<<<(BB*NN)/8, 256, 0, stream>>>(xp, ctx, ln2_g, ln2_b, ffW1, ffb1, ffW2, ffb2, out);
}

// Round 17
// 65.810 us; speedup vs baseline: 1.3203x; 1.2143x over previous
//
#include <hip/hip_runtime.h>
#include <hip/hip_bf16.h>

#define BB 8
#define NN 512
#define DINC 128
#define DOUTC 128
#define HHC 8
#define EEC 16
#define DHC 16

typedef _Float16 h4 __attribute__((ext_vector_type(4)));
typedef float f32x4 __attribute__((ext_vector_type(4)));

__device__ __forceinline__ float wsum(float v){
#pragma unroll
  for (int o=1;o<64;o<<=1) v += __shfl_xor(v,o);
  return v;
}

// ---------- one-shot weight swizzle: fragment-order f16 tables ----------
// Kills the 17M scattered 4B weight gathers in proj/ffn/edge (G13): each MFMA
// fragment becomes ONE coalesced 8B h4 load. Bitwise-same values (same cast).
__global__ __launch_bounds__(256) void k_prep(
  const float* __restrict__ Wp, const float* __restrict__ Wq,
  const float* __restrict__ Wk, const float* __restrict__ Wv,
  const float* __restrict__ ffW1, const float* __restrict__ ffW2,
  const float* __restrict__ We1, const float* __restrict__ We2,
  _Float16* __restrict__ Wps, _Float16* __restrict__ Wqs,
  _Float16* __restrict__ Wks, _Float16* __restrict__ Wvs,
  _Float16* __restrict__ W1s, _Float16* __restrict__ W2s,
  _Float16* __restrict__ Wes)
{
  int id = blockIdx.x*256 + threadIdx.x;
  if (id < 32768){                       // ffW1: [ht<16][kt<8][lane][j]
    int j=id&3, lane=(id>>2)&63, kt=(id>>8)&7, ht=id>>11;
    int c=lane&15, g=lane>>4;
    W1s[id] = (_Float16)ffW1[(16*kt+4*g+j)*256 + 16*ht + c];
  } else if (id < 65536){                // ffW2: [ot<8][kt2<16][lane][j]
    int e=id-32768; int j=e&3, lane=(e>>2)&63, kt2=(e>>8)&15, ot=e>>12;
    int c=lane&15, g=lane>>4;
    W2s[e] = (_Float16)ffW2[(16*kt2+4*g+j)*128 + 16*ot + c];
  } else if (id < 131072){               // Wp/Wq/Wk/Wv: [ot<8][kt<8][lane][j]
    int e=id-65536; int sel=e>>14; e&=16383;
    int j=e&3, lane=(e>>2)&63, kt=(e>>8)&7, ot=e>>11;
    int c=lane&15, g=lane>>4;
    const float* W = (sel==0)?Wp:((sel==1)?Wq:((sel==2)?Wk:Wv));
    _Float16* D   = (sel==0)?Wps:((sel==1)?Wqs:((sel==2)?Wks:Wvs));
    D[e] = (_Float16)W[(16*kt+4*g+j)*128 + 16*ot + c];
  } else if (id < 132096){               // edge We1/We2 fragment tables (4x 256)
    int e=id-131072; int tbl=e>>8; int r=e&255;
    int lane=r>>2, j=r&3, c=lane&15, g=lane>>4;
    float v;
    if (tbl==0)      v = We1[(4*g+j)*32 + c];
    else if (tbl==1) v = We1[(4*g+j)*32 + 16 + c];
    else if (tbl==2) v = (c<8)? We2[(4*g+j)*HHC + c] : 0.f;
    else             v = (c<8)? We2[(16+4*g+j)*HHC + c] : 0.f;
    Wes[e] = (_Float16)v;
  }
}

// ---------- proj v3: R11/R16 structure, swizzled-f16 weight loads ----------
__global__ __launch_bounds__(256) void k_proj(
    const float* __restrict__ x,
    const float* __restrict__ g1, const float* __restrict__ b1,
    const _Float16* __restrict__ Wps, const float* __restrict__ bp,
    const _Float16* __restrict__ Wqs, const _Float16* __restrict__ Wks, const _Float16* __restrict__ Wvs,
    float* __restrict__ xp, _Float16* __restrict__ Qh, _Float16* __restrict__ Kh, _Float16* __restrict__ Vh)
{
  __shared__ _Float16 xln[16][136];
  __shared__ _Float16 xps[16][136];
  __shared__ float    xp32[16][132];
  __shared__ _Float16 qs[3][16][136];
  int tid=threadIdx.x, w=tid>>6, lane=tid&63;
  int c=lane&15, g=lane>>4;
  int row0 = blockIdx.x*16;
  int b = row0>>9, n0 = row0&(NN-1);

  float ga=g1[lane], gb=g1[lane+64], ba=b1[lane], bbx=b1[lane+64];
#pragma unroll
  for (int rr=0;rr<4;++rr){
    int r = w + rr*4;
    size_t gi = (size_t)(row0+r)*DINC + lane;
    float a = x[gi], cc = x[gi+64];
    float s = wsum(a+cc);
    float q = wsum(a*a+cc*cc);
    float mean = s*(1.f/DINC);
    float var  = q*(1.f/DINC)-mean*mean;
    float rstd = rsqrtf(var+1e-5f);
    xln[r][lane]    = (_Float16)((a -mean)*rstd*ga + ba);
    xln[r][lane+64] = (_Float16)((cc-mean)*rstd*gb + bbx);
  }
  __syncthreads();

#pragma unroll
  for (int oo=0;oo<2;++oo){
    int ot = 2*w+oo;
    float4 bi = *(const float4*)(bp + 16*ot + 4*g);
    f32x4 D; D[0]=bi.x; D[1]=bi.y; D[2]=bi.z; D[3]=bi.w;
#pragma unroll
    for (int kt=0;kt<8;++kt){
      h4 f = *(const h4*)(Wps + (size_t)((ot*8+kt)*64 + lane)*4);
      h4 hb = *(const h4*)&xln[c][16*kt+4*g];
      D = __builtin_amdgcn_mfma_f32_16x16x16f16(f, hb, D, 0,0,0);
    }
#pragma unroll
    for (int r=0;r<4;++r){
      xp32[c][16*ot+4*g+r] = D[r];
      xps [c][16*ot+4*g+r] = (_Float16)D[r];
    }
  }
  __syncthreads();

#pragma unroll
  for (int pp=0;pp<6;++pp){
    int p = w + pp*4;
    int mat = p>>3, ot = p&7;
    const _Float16* W = (mat==0)? Wqs : ((mat==1)? Wks : Wvs);
    f32x4 D = {0.f,0.f,0.f,0.f};
#pragma unroll
    for (int kt=0;kt<8;++kt){
      h4 f = *(const h4*)(W + (size_t)((ot*8+kt)*64 + lane)*4);
      h4 hb = *(const h4*)&xps[c][16*kt+4*g];
      D = __builtin_amdgcn_mfma_f32_16x16x16f16(f, hb, D, 0,0,0);
    }
#pragma unroll
    for (int r=0;r<4;++r)
      qs[mat][c][16*ot+4*g+r] = (_Float16)D[r];
  }
  __syncthreads();

#pragma unroll
  for (int i=tid;i<512;i+=256){
    int r=i>>5, seg=i&31;
    *(float4*)(xp + (size_t)(row0+r)*DOUTC + seg*4) = *(const float4*)&xp32[r][seg*4];
  }
#pragma unroll
  for (int mat=0;mat<3;++mat){
    int r = tid>>4, seg = tid&15;
    int h = seg>>1, d = (seg&1)*8;
    _Float16* O = (mat==0)? Qh : ((mat==1)? Kh : Vh);
    *(float4*)(O + (((size_t)b*HHC+h)*NN + n0+r)*DHC + d) = *(const float4*)&qs[mat][r][seg*8];
  }
}

// ---------- edge-bias MLP v7b (R16 + swizzled weight-fragment loads) ----------
__global__ __launch_bounds__(256) void k_edge(
  const float* __restrict__ ea, const int* __restrict__ adj,
  const float* __restrict__ eg, const float* __restrict__ ebi,
  const _Float16* __restrict__ Wes, const float* __restrict__ be1,
  const float* __restrict__ be2,
  _Float16* __restrict__ ebias)
{
  __shared__ _Float16 stage[8][520];
  __shared__ unsigned long long msk[8];
  __shared__ unsigned short idx16[512];
  __shared__ int cntS;

  int tid = threadIdx.x, w = tid>>6, lane = tid&63;
  int c = lane&15, g = lane>>4;
  int bn = blockIdx.x;
  int b = bn >> 9, n = bn & (NN-1);

  const int* adjRow = adj + (size_t)bn*NN;
  int col1 = tid, col2 = tid + 256;
  int v1 = (adjRow[col1] != 0) || (col1 == n);
  int v2 = (adjRow[col2] != 0) || (col2 == n);
  unsigned long long b1m = __ballot(v1);
  unsigned long long b2m = __ballot(v2);
  if (lane==0){ msk[w] = b1m; msk[4+w] = b2m; }

  // fragment tables: 4 coalesced 8B loads (was 16 scattered 4B gathers)
  h4 w1a = *(const h4*)(Wes +        lane*4);
  h4 w1b = *(const h4*)(Wes + 256  + lane*4);
  h4 w2a = *(const h4*)(Wes + 512  + lane*4);
  h4 w2b = *(const h4*)(Wes + 768  + lane*4);
  float4 b1a = *(const float4*)(be1 + 4*g);
  float4 b1b = *(const float4*)(be1 + 16 + 4*g);
  float4 b2r = *(const float4*)(be2 + (g&1)*4);
  float4 G4  = *(const float4*)(eg  + 4*g);
  float4 Bv4 = *(const float4*)(ebi + 4*g);

  __syncthreads();

  int offs[8]; int cnt = 0;
#pragma unroll
  for (int k=0;k<8;++k){ offs[k] = cnt; cnt += __popcll(msk[k]); }
  if (tid==0) cntS = cnt;

  { // prefill stage with -30000, 16B writes
    _Float16 neg = (_Float16)(-30000.f);
    _Float16 nv8[8] = {neg,neg,neg,neg,neg,neg,neg,neg};
    float4 negv = *(const float4*)nv8;
#pragma unroll
    for (int i=tid;i<512;i+=256){
      int h = i>>6, m8 = i&63;
      *(float4*)&stage[h][m8*8] = negv;
    }
  }

  if (v1){
    int pos = offs[w]   + __popcll(msk[w]   & ((1ull<<lane)-1ull));
    idx16[pos] = (unsigned short)col1;
  }
  if (v2){
    int pos = offs[4+w] + __popcll(msk[4+w] & ((1ull<<lane)-1ull));
    idx16[pos] = (unsigned short)col2;
  }
  __syncthreads();

  cnt = cntS;
  int nt = (cnt + 15) >> 4;
  const float* eaRow = ea + (size_t)bn*NN*EEC;

  for (int t = w; t < nt; t += 4){
    int slot = 16*t + c;
    int sidx = slot < cnt ? slot : cnt-1;
    int idx  = idx16[sidx];
    float4 v = *(const float4*)(eaRow + (size_t)idx*EEC + 4*g);
    float s = v.x+v.y+v.z+v.w;
    float q = v.x*v.x+v.y*v.y+v.z*v.z+v.w*v.w;
    s += __shfl_xor(s,16); s += __shfl_xor(s,32);
    q += __shfl_xor(q,16); q += __shfl_xor(q,32);
    float mean = s*(1.f/EEC);
    float var  = q*(1.f/EEC) - mean*mean;
    float rstd = rsqrtf(var + 1e-5f);
    h4 ef;
    ef[0]=(_Float16)((v.x-mean)*rstd*G4.x + Bv4.x);
    ef[1]=(_Float16)((v.y-mean)*rstd*G4.y + Bv4.y);
    ef[2]=(_Float16)((v.z-mean)*rstd*G4.z + Bv4.z);
    ef[3]=(_Float16)((v.w-mean)*rstd*G4.w + Bv4.w);
    f32x4 d1a = {b1a.x,b1a.y,b1a.z,b1a.w};
    f32x4 d1b = {b1b.x,b1b.y,b1b.z,b1b.w};
    d1a = __builtin_amdgcn_mfma_f32_16x16x16f16(w1a, ef, d1a, 0,0,0);
    d1b = __builtin_amdgcn_mfma_f32_16x16x16f16(w1b, ef, d1b, 0,0,0);
    h4 hfa,hfb;
#pragma unroll
    for (int r=0;r<4;++r){
      hfa[r]=(_Float16)fmaxf(d1a[r],0.f);
      hfb[r]=(_Float16)fmaxf(d1b[r],0.f);
    }
    f32x4 d2 = {0.f,0.f,0.f,0.f};
    d2 = __builtin_amdgcn_mfma_f32_16x16x16f16(w2a, hfa, d2, 0,0,0);
    d2 = __builtin_amdgcn_mfma_f32_16x16x16f16(w2b, hfb, d2, 0,0,0);
    if (g<2 && slot<cnt){
#pragma unroll
      for (int r=0;r<4;++r){
        float y = d2[r] + ((const float*)&b2r)[r];
        y = fminf(fmaxf(2.f*y,-30.f),30.f);
        float ex = __expf(y);
        float t2 = __fdividef(ex-1.f, ex+1.f);   // fast tanh ratio
        stage[4*g+r][idx] = (_Float16)(5.f*t2);
      }
    }
  }
  __syncthreads();

  size_t base = ((size_t)b*HHC)*NN*NN + (size_t)n*NN;
#pragma unroll
  for (int i=tid;i<512;i+=256){
    int h = i>>6, m8 = i&63;
    *(float4*)(ebias + base + (size_t)h*NN*NN + m8*8) =
        *(const float4*)&stage[h][m8*8];
  }
}

// ---------- MFMA attention v3 (R16): K direct from L2, V-only LDS ----------
__global__ __launch_bounds__(256) void k_attn(
  const _Float16* __restrict__ Qh, const _Float16* __restrict__ Kh, const _Float16* __restrict__ Vh,
  const _Float16* __restrict__ eb, float* __restrict__ ctxb)
{
  __shared__ _Float16 Vt[DHC*520];
  int tid = threadIdx.x;
  int bh   = blockIdx.x >> 3;
  int tile = blockIdx.x & 7;
  const _Float16* Vg = Vh + (size_t)bh*NN*DHC;
  {
#pragma unroll
    for (int i=tid;i<1024;i+=256){
      int m = i>>1, hf = i&1;
      float4 v4 = *(const float4*)(Vg + (size_t)m*DHC + hf*8);
      const _Float16* hh = (const _Float16*)&v4;
#pragma unroll
      for (int jj=0;jj<8;++jj) Vt[(hf*8+jj)*520 + m] = hh[jj];
    }
  }
  __syncthreads();

  int w = tid>>6, lane = tid&63;
  int c = lane&15, g = lane>>4;
  int n0 = tile*64 + w*16;

  h4 qf = *(const h4*)(Qh + ((size_t)bh*NN + n0 + c)*DHC + 4*g);
  const _Float16* ebw = eb + ((size_t)bh*NN + n0 + c)*NN + 4*g;
  const _Float16* Kb  = Kh + (size_t)bh*NN*DHC;

  f32x4 zero = {0.f,0.f,0.f,0.f};
  f32x4 acc = zero;
  float rowsum = 0.f;
#pragma unroll
  for (int t=0;t<32;++t){
    h4 kf = *(const h4*)(Kb + (size_t)(16*t + c)*DHC + 4*g);
    f32x4 d = __builtin_amdgcn_mfma_f32_16x16x16f16(kf, qf, zero, 0, 0, 0);
    h4 e4 = *(const h4*)(ebw + 16*t);
    h4 pa;
#pragma unroll
    for (int r=0;r<4;++r){
      float sv = d[r]*0.25f + (float)e4[r];
      sv = fmaxf(sv,0.f) + 0.2f*fminf(sv,0.f);
      float p = __expf(sv - 6.f);
      rowsum += p;
      pa[r] = (_Float16)p;
    }
    h4 vf = *(const h4*)(Vt + c*520 + 16*t + 4*g);
    acc = __builtin_amdgcn_mfma_f32_16x16x16f16(pa, vf, acc, 0, 0, 0);
  }
  rowsum += __shfl_xor(rowsum,16);
  rowsum += __shfl_xor(rowsum,32);

  int b = bh>>3, h = bh&7;
#pragma unroll
  for (int r=0;r<4;++r){
    float sr = __shfl(rowsum, g*16 + 4*g + r);
    ctxb[((size_t)b*NN + n0 + 4*g + r)*DOUTC + h*DHC + c] = acc[r]/sr;
  }
}

// ---------- FFN v5: R11 structure, swizzled-f16 weight loads ----------
__global__ __launch_bounds__(256) void k_ffn(
  const float* __restrict__ xp, const float* __restrict__ ctxb,
  const float* __restrict__ g2, const float* __restrict__ b2v,
  const _Float16* __restrict__ W1s, const float* __restrict__ bb1,
  const _Float16* __restrict__ W2s, const float* __restrict__ bb2,
  float* __restrict__ out)
{
  __shared__ float    hrow[8][DOUTC];
  __shared__ _Float16 hn[16][136];
  __shared__ float    part[4][8][16][16];

  int tid = threadIdx.x, w = tid>>6, lane = tid&63;
  int c = lane&15, g = lane>>4;
  int n0 = blockIdx.x * 8;

#pragma unroll
  for (int i=tid;i<272;i+=256){
    h4 z = {(_Float16)0.f,(_Float16)0.f,(_Float16)0.f,(_Float16)0.f};
    ((h4*)hn)[272+i] = z;
  }

  float ga=g2[lane], gb=g2[lane+64], ba=b2v[lane], bbx=b2v[lane+64];
#pragma unroll
  for (int rr=0;rr<2;++rr){
    int r = w + rr*4;
    size_t gi = (size_t)(n0+r)*DOUTC + lane;
    float a  = xp[gi]    + ctxb[gi];
    float cc = xp[gi+64] + ctxb[gi+64];
    hrow[r][lane] = a; hrow[r][lane+64] = cc;
    float s = wsum(a+cc);
    float q = wsum(a*a+cc*cc);
    float mean = s*(1.f/DOUTC);
    float var  = q*(1.f/DOUTC) - mean*mean;
    float rstd = rsqrtf(var + 1e-5f);
    hn[r][lane]    = (_Float16)((a -mean)*rstd*ga + ba);
    hn[r][lane+64] = (_Float16)((cc-mean)*rstd*gb + bbx);
  }
  __syncthreads();

  h4 hidB[4];
#pragma unroll
  for (int t=0;t<4;++t){
    int ht = 4*w + t;
    float4 bi = *(const float4*)(bb1 + 16*ht + 4*g);
    f32x4 D1; D1[0]=bi.x; D1[1]=bi.y; D1[2]=bi.z; D1[3]=bi.w;
#pragma unroll
    for (int kt=0;kt<8;++kt){
      h4 f = *(const h4*)(W1s + (size_t)((ht*8+kt)*64 + lane)*4);
      h4 hb = *(const h4*)&hn[c][16*kt + 4*g];
      D1 = __builtin_amdgcn_mfma_f32_16x16x16f16(f, hb, D1, 0,0,0);
    }
#pragma unroll
    for (int r=0;r<4;++r) hidB[t][r] = (_Float16)fmaxf(D1[r], 0.f);
  }

#pragma unroll
  for (int ot=0;ot<8;++ot){
    f32x4 d2 = {0.f,0.f,0.f,0.f};
#pragma unroll
    for (int t=0;t<4;++t){
      h4 f = *(const h4*)(W2s + (size_t)((ot*16 + 4*w + t)*64 + lane)*4);
      d2 = __builtin_amdgcn_mfma_f32_16x16x16f16(f, hidB[t], d2, 0,0,0);
    }
#pragma unroll
    for (int r=0;r<4;++r) part[w][ot][4*g+r][c] = d2[r];
  }
  __syncthreads();

#pragma unroll
  for (int i=tid;i<1024;i+=256){
    int n = i>>7, col = i&127;
    int ot = col>>4, m = col&15;
    float v = part[0][ot][m][n] + part[1][ot][m][n]
            + part[2][ot][m][n] + part[3][ot][m][n];
    out[(size_t)(n0+n)*DOUTC + col] = hrow[n][col] + v + bb2[col];
  }
}

extern "C" void kernel_launch(void* const* d_in, const int* in_sizes, int n_in,
                              void* d_out, int out_size, void* d_ws, size_t ws_size,
                              hipStream_t stream)
{
  const float* x     = (const float*)d_in[0];
  const int*   adj   = (const int*)  d_in[1];
  const float* ea    = (const float*)d_in[2];
  const float* ln1_g = (const float*)d_in[3];
  const float* ln1_b = (const float*)d_in[4];
  const float* Wp    = (const float*)d_in[5];
  const float* bp    = (const float*)d_in[6];
  const float* eln_g = (const float*)d_in[7];
  const float* eln_b = (const float*)d_in[8];
  const float* We1   = (const float*)d_in[9];
  const float* be1   = (const float*)d_in[10];
  const float* We2   = (const float*)d_in[11];
  const float* be2   = (const float*)d_in[12];
  const float* Wq    = (const float*)d_in[13];
  const float* Wk    = (const float*)d_in[14];
  const float* Wv    = (const float*)d_in[15];
  const float* ffW1  = (const float*)d_in[16];
  const float* ffb1  = (const float*)d_in[17];
  const float* ffW2  = (const float*)d_in[18];
  const float* ffb2  = (const float*)d_in[19];
  const float* ln2_g = (const float*)d_in[20];
  const float* ln2_b = (const float*)d_in[21];
  float* out = (float*)d_out;

  char* ws = (char*)d_ws;
  float*    xp  = (float*)(ws);                       // 2MB (f32)
  float*    ctx = (float*)(ws + ((size_t)2<<20));     // 2MB
  _Float16* Qh  = (_Float16*)(ws + ((size_t)4<<20));  // 1MB
  _Float16* Kh  = (_Float16*)(ws + ((size_t)5<<20));  // 1MB
  _Float16* Vh  = (_Float16*)(ws + ((size_t)6<<20));  // 1MB
  _Float16* ebf = (_Float16*)(ws + ((size_t)7<<20));  // 32MB [B,H,N,N] f16
  char* wsw = ws + ((size_t)39<<20);                  // swizzled weights (258KB)
  _Float16* W1s = (_Float16*)(wsw);                   // 64KB
  _Float16* W2s = (_Float16*)(wsw + 65536);           // 64KB
  _Float16* Wps = (_Float16*)(wsw + 131072);          // 32KB
  _Float16* Wqs = (_Float16*)(wsw + 163840);          // 32KB
  _Float16* Wks = (_Float16*)(wsw + 196608);          // 32KB
  _Float16* Wvs = (_Float16*)(wsw + 229376);          // 32KB
  _Float16* Wes = (_Float16*)(wsw + 262144);          // 2KB

  k_prep<<<516, 256, 0, stream>>>(Wp, Wq, Wk, Wv, ffW1, ffW2, We1, We2,
                                  Wps, Wqs, Wks, Wvs, W1s, W2s, Wes);
  k_proj<<<(BB*NN)/16, 256, 0, stream>>>(x, ln1_g, ln1_b, Wps, bp, Wqs, Wks, Wvs, xp, Qh, Kh, Vh);
  k_edge<<<BB*NN, 256, 0, stream>>>(ea, adj, eln_g, eln_b, Wes, be1, be2, ebf);
  k_attn<<<BB*HHC*8, 256, 0, stream>>>(Qh, Kh, Vh, ebf, ctx);
  k_ffn<<<(BB*NN)/8, 256, 0, stream>>>(xp, ctx, ln2_g, ln2_b, W1s, ffb1, W2s, ffb2, out);
}

// Round 18
// 65.271 us; speedup vs baseline: 1.3312x; 1.0083x over previous
//
#include <hip/hip_runtime.h>
#include <hip/hip_bf16.h>

#define BB 8
#define NN 512
#define DINC 128
#define DOUTC 128
#define HHC 8
#define EEC 16
#define DHC 16

typedef _Float16 h4 __attribute__((ext_vector_type(4)));
typedef float f32x4 __attribute__((ext_vector_type(4)));

__device__ __forceinline__ float wsum(float v){
#pragma unroll
  for (int o=1;o<64;o<<=1) v += __shfl_xor(v,o);
  return v;
}

// ---------- one-shot weight swizzle (R17-verified): fragment-order f16 tables ----------
__global__ __launch_bounds__(256) void k_prep(
  const float* __restrict__ Wp, const float* __restrict__ Wq,
  const float* __restrict__ Wk, const float* __restrict__ Wv,
  const float* __restrict__ ffW1, const float* __restrict__ ffW2,
  const float* __restrict__ We1, const float* __restrict__ We2,
  _Float16* __restrict__ Wps, _Float16* __restrict__ Wqs,
  _Float16* __restrict__ Wks, _Float16* __restrict__ Wvs,
  _Float16* __restrict__ W1s, _Float16* __restrict__ W2s,
  _Float16* __restrict__ Wes)
{
  int id = blockIdx.x*256 + threadIdx.x;
  if (id < 32768){                       // ffW1: [ht<16][kt<8][lane][j]
    int j=id&3, lane=(id>>2)&63, kt=(id>>8)&7, ht=id>>11;
    int c=lane&15, g=lane>>4;
    W1s[id] = (_Float16)ffW1[(16*kt+4*g+j)*256 + 16*ht + c];
  } else if (id < 65536){                // ffW2: [ot<8][kt2<16][lane][j]
    int e=id-32768; int j=e&3, lane=(e>>2)&63, kt2=(e>>8)&15, ot=e>>12;
    int c=lane&15, g=lane>>4;
    W2s[e] = (_Float16)ffW2[(16*kt2+4*g+j)*128 + 16*ot + c];
  } else if (id < 131072){               // Wp/Wq/Wk/Wv: [ot<8][kt<8][lane][j]
    int e=id-65536; int sel=e>>14; e&=16383;
    int j=e&3, lane=(e>>2)&63, kt=(e>>8)&7, ot=e>>11;
    int c=lane&15, g=lane>>4;
    const float* W = (sel==0)?Wp:((sel==1)?Wq:((sel==2)?Wk:Wv));
    _Float16* D   = (sel==0)?Wps:((sel==1)?Wqs:((sel==2)?Wks:Wvs));
    D[e] = (_Float16)W[(16*kt+4*g+j)*128 + 16*ot + c];
  } else if (id < 132096){               // edge We1/We2 fragment tables (4x 256)
    int e=id-131072; int tbl=e>>8; int r=e&255;
    int lane=r>>2, j=r&3, c=lane&15, g=lane>>4;
    float v;
    if (tbl==0)      v = We1[(4*g+j)*32 + c];
    else if (tbl==1) v = We1[(4*g+j)*32 + 16 + c];
    else if (tbl==2) v = (c<8)? We2[(4*g+j)*HHC + c] : 0.f;
    else             v = (c<8)? We2[(16+4*g+j)*HHC + c] : 0.f;
    Wes[e] = (_Float16)v;
  }
}

// ---------- proj v3 (R17-verified): swizzled-f16 weight loads ----------
__global__ __launch_bounds__(256) void k_proj(
    const float* __restrict__ x,
    const float* __restrict__ g1, const float* __restrict__ b1,
    const _Float16* __restrict__ Wps, const float* __restrict__ bp,
    const _Float16* __restrict__ Wqs, const _Float16* __restrict__ Wks, const _Float16* __restrict__ Wvs,
    float* __restrict__ xp, _Float16* __restrict__ Qh, _Float16* __restrict__ Kh, _Float16* __restrict__ Vh)
{
  __shared__ _Float16 xln[16][136];
  __shared__ _Float16 xps[16][136];
  __shared__ float    xp32[16][132];
  __shared__ _Float16 qs[3][16][136];
  int tid=threadIdx.x, w=tid>>6, lane=tid&63;
  int c=lane&15, g=lane>>4;
  int row0 = blockIdx.x*16;
  int b = row0>>9, n0 = row0&(NN-1);

  float ga=g1[lane], gb=g1[lane+64], ba=b1[lane], bbx=b1[lane+64];
#pragma unroll
  for (int rr=0;rr<4;++rr){
    int r = w + rr*4;
    size_t gi = (size_t)(row0+r)*DINC + lane;
    float a = x[gi], cc = x[gi+64];
    float s = wsum(a+cc);
    float q = wsum(a*a+cc*cc);
    float mean = s*(1.f/DINC);
    float var  = q*(1.f/DINC)-mean*mean;
    float rstd = rsqrtf(var+1e-5f);
    xln[r][lane]    = (_Float16)((a -mean)*rstd*ga + ba);
    xln[r][lane+64] = (_Float16)((cc-mean)*rstd*gb + bbx);
  }
  __syncthreads();

#pragma unroll
  for (int oo=0;oo<2;++oo){
    int ot = 2*w+oo;
    float4 bi = *(const float4*)(bp + 16*ot + 4*g);
    f32x4 D; D[0]=bi.x; D[1]=bi.y; D[2]=bi.z; D[3]=bi.w;
#pragma unroll
    for (int kt=0;kt<8;++kt){
      h4 f = *(const h4*)(Wps + (size_t)((ot*8+kt)*64 + lane)*4);
      h4 hb = *(const h4*)&xln[c][16*kt+4*g];
      D = __builtin_amdgcn_mfma_f32_16x16x16f16(f, hb, D, 0,0,0);
    }
#pragma unroll
    for (int r=0;r<4;++r){
      xp32[c][16*ot+4*g+r] = D[r];
      xps [c][16*ot+4*g+r] = (_Float16)D[r];
    }
  }
  __syncthreads();

#pragma unroll
  for (int pp=0;pp<6;++pp){
    int p = w + pp*4;
    int mat = p>>3, ot = p&7;
    const _Float16* W = (mat==0)? Wqs : ((mat==1)? Wks : Wvs);
    f32x4 D = {0.f,0.f,0.f,0.f};
#pragma unroll
    for (int kt=0;kt<8;++kt){
      h4 f = *(const h4*)(W + (size_t)((ot*8+kt)*64 + lane)*4);
      h4 hb = *(const h4*)&xps[c][16*kt+4*g];
      D = __builtin_amdgcn_mfma_f32_16x16x16f16(f, hb, D, 0,0,0);
    }
#pragma unroll
    for (int r=0;r<4;++r)
      qs[mat][c][16*ot+4*g+r] = (_Float16)D[r];
  }
  __syncthreads();

#pragma unroll
  for (int i=tid;i<512;i+=256){
    int r=i>>5, seg=i&31;
    *(float4*)(xp + (size_t)(row0+r)*DOUTC + seg*4) = *(const float4*)&xp32[r][seg*4];
  }
#pragma unroll
  for (int mat=0;mat<3;++mat){
    int r = tid>>4, seg = tid&15;
    int h = seg>>1, d = (seg&1)*8;
    _Float16* O = (mat==0)? Qh : ((mat==1)? Kh : Vh);
    *(float4*)(O + (((size_t)b*HHC+h)*NN + n0+r)*DHC + d) = *(const float4*)&qs[mat][r][seg*8];
  }
}

// ---------- edge-bias MLP v7b (R17-verified) ----------
__global__ __launch_bounds__(256) void k_edge(
  const float* __restrict__ ea, const int* __restrict__ adj,
  const float* __restrict__ eg, const float* __restrict__ ebi,
  const _Float16* __restrict__ Wes, const float* __restrict__ be1,
  const float* __restrict__ be2,
  _Float16* __restrict__ ebias)
{
  __shared__ _Float16 stage[8][520];
  __shared__ unsigned long long msk[8];
  __shared__ unsigned short idx16[512];
  __shared__ int cntS;

  int tid = threadIdx.x, w = tid>>6, lane = tid&63;
  int c = lane&15, g = lane>>4;
  int bn = blockIdx.x;
  int b = bn >> 9, n = bn & (NN-1);

  const int* adjRow = adj + (size_t)bn*NN;
  int col1 = tid, col2 = tid + 256;
  int v1 = (adjRow[col1] != 0) || (col1 == n);
  int v2 = (adjRow[col2] != 0) || (col2 == n);
  unsigned long long b1m = __ballot(v1);
  unsigned long long b2m = __ballot(v2);
  if (lane==0){ msk[w] = b1m; msk[4+w] = b2m; }

  h4 w1a = *(const h4*)(Wes +        lane*4);
  h4 w1b = *(const h4*)(Wes + 256  + lane*4);
  h4 w2a = *(const h4*)(Wes + 512  + lane*4);
  h4 w2b = *(const h4*)(Wes + 768  + lane*4);
  float4 b1a = *(const float4*)(be1 + 4*g);
  float4 b1b = *(const float4*)(be1 + 16 + 4*g);
  float4 b2r = *(const float4*)(be2 + (g&1)*4);
  float4 G4  = *(const float4*)(eg  + 4*g);
  float4 Bv4 = *(const float4*)(ebi + 4*g);

  __syncthreads();

  int offs[8]; int cnt = 0;
#pragma unroll
  for (int k=0;k<8;++k){ offs[k] = cnt; cnt += __popcll(msk[k]); }
  if (tid==0) cntS = cnt;

  {
    _Float16 neg = (_Float16)(-30000.f);
    _Float16 nv8[8] = {neg,neg,neg,neg,neg,neg,neg,neg};
    float4 negv = *(const float4*)nv8;
#pragma unroll
    for (int i=tid;i<512;i+=256){
      int h = i>>6, m8 = i&63;
      *(float4*)&stage[h][m8*8] = negv;
    }
  }

  if (v1){
    int pos = offs[w]   + __popcll(msk[w]   & ((1ull<<lane)-1ull));
    idx16[pos] = (unsigned short)col1;
  }
  if (v2){
    int pos = offs[4+w] + __popcll(msk[4+w] & ((1ull<<lane)-1ull));
    idx16[pos] = (unsigned short)col2;
  }
  __syncthreads();

  cnt = cntS;
  int nt = (cnt + 15) >> 4;
  const float* eaRow = ea + (size_t)bn*NN*EEC;

  for (int t = w; t < nt; t += 4){
    int slot = 16*t + c;
    int sidx = slot < cnt ? slot : cnt-1;
    int idx  = idx16[sidx];
    float4 v = *(const float4*)(eaRow + (size_t)idx*EEC + 4*g);
    float s = v.x+v.y+v.z+v.w;
    float q = v.x*v.x+v.y*v.y+v.z*v.z+v.w*v.w;
    s += __shfl_xor(s,16); s += __shfl_xor(s,32);
    q += __shfl_xor(q,16); q += __shfl_xor(q,32);
    float mean = s*(1.f/EEC);
    float var  = q*(1.f/EEC) - mean*mean;
    float rstd = rsqrtf(var + 1e-5f);
    h4 ef;
    ef[0]=(_Float16)((v.x-mean)*rstd*G4.x + Bv4.x);
    ef[1]=(_Float16)((v.y-mean)*rstd*G4.y + Bv4.y);
    ef[2]=(_Float16)((v.z-mean)*rstd*G4.z + Bv4.z);
    ef[3]=(_Float16)((v.w-mean)*rstd*G4.w + Bv4.w);
    f32x4 d1a = {b1a.x,b1a.y,b1a.z,b1a.w};
    f32x4 d1b = {b1b.x,b1b.y,b1b.z,b1b.w};
    d1a = __builtin_amdgcn_mfma_f32_16x16x16f16(w1a, ef, d1a, 0,0,0);
    d1b = __builtin_amdgcn_mfma_f32_16x16x16f16(w1b, ef, d1b, 0,0,0);
    h4 hfa,hfb;
#pragma unroll
    for (int r=0;r<4;++r){
      hfa[r]=(_Float16)fmaxf(d1a[r],0.f);
      hfb[r]=(_Float16)fmaxf(d1b[r],0.f);
    }
    f32x4 d2 = {0.f,0.f,0.f,0.f};
    d2 = __builtin_amdgcn_mfma_f32_16x16x16f16(w2a, hfa, d2, 0,0,0);
    d2 = __builtin_amdgcn_mfma_f32_16x16x16f16(w2b, hfb, d2, 0,0,0);
    if (g<2 && slot<cnt){
#pragma unroll
      for (int r=0;r<4;++r){
        float y = d2[r] + ((const float*)&b2r)[r];
        y = fminf(fmaxf(2.f*y,-30.f),30.f);
        float ex = __expf(y);
        float t2 = __fdividef(ex-1.f, ex+1.f);   // fast tanh ratio
        stage[4*g+r][idx] = (_Float16)(5.f*t2);
      }
    }
  }
  __syncthreads();

  size_t base = ((size_t)b*HHC)*NN*NN + (size_t)n*NN;
#pragma unroll
  for (int i=tid;i<512;i+=256){
    int h = i>>6, m8 = i&63;
    *(float4*)(ebias + base + (size_t)h*NN*NN + m8*8) =
        *(const float4*)&stage[h][m8*8];
  }
}

// ---------- MFMA attention v3 (R16/R17-verified) ----------
__global__ __launch_bounds__(256) void k_attn(
  const _Float16* __restrict__ Qh, const _Float16* __restrict__ Kh, const _Float16* __restrict__ Vh,
  const _Float16* __restrict__ eb, float* __restrict__ ctxb)
{
  __shared__ _Float16 Vt[DHC*520];
  int tid = threadIdx.x;
  int bh   = blockIdx.x >> 3;
  int tile = blockIdx.x & 7;
  const _Float16* Vg = Vh + (size_t)bh*NN*DHC;
  {
#pragma unroll
    for (int i=tid;i<1024;i+=256){
      int m = i>>1, hf = i&1;
      float4 v4 = *(const float4*)(Vg + (size_t)m*DHC + hf*8);
      const _Float16* hh = (const _Float16*)&v4;
#pragma unroll
      for (int jj=0;jj<8;++jj) Vt[(hf*8+jj)*520 + m] = hh[jj];
    }
  }
  __syncthreads();

  int w = tid>>6, lane = tid&63;
  int c = lane&15, g = lane>>4;
  int n0 = tile*64 + w*16;

  h4 qf = *(const h4*)(Qh + ((size_t)bh*NN + n0 + c)*DHC + 4*g);
  const _Float16* ebw = eb + ((size_t)bh*NN + n0 + c)*NN + 4*g;
  const _Float16* Kb  = Kh + (size_t)bh*NN*DHC;

  f32x4 zero = {0.f,0.f,0.f,0.f};
  f32x4 acc = zero;
  float rowsum = 0.f;
#pragma unroll
  for (int t=0;t<32;++t){
    h4 kf = *(const h4*)(Kb + (size_t)(16*t + c)*DHC + 4*g);
    f32x4 d = __builtin_amdgcn_mfma_f32_16x16x16f16(kf, qf, zero, 0, 0, 0);
    h4 e4 = *(const h4*)(ebw + 16*t);
    h4 pa;
#pragma unroll
    for (int r=0;r<4;++r){
      float sv = d[r]*0.25f + (float)e4[r];
      sv = fmaxf(sv,0.f) + 0.2f*fminf(sv,0.f);
      float p = __expf(sv - 6.f);
      rowsum += p;
      pa[r] = (_Float16)p;
    }
    h4 vf = *(const h4*)(Vt + c*520 + 16*t + 4*g);
    acc = __builtin_amdgcn_mfma_f32_16x16x16f16(pa, vf, acc, 0, 0, 0);
  }
  rowsum += __shfl_xor(rowsum,16);
  rowsum += __shfl_xor(rowsum,32);

  int b = bh>>3, h = bh&7;
#pragma unroll
  for (int r=0;r<4;++r){
    float sr = __shfl(rowsum, g*16 + 4*g + r);
    ctxb[((size_t)b*NN + n0 + 4*g + r)*DOUTC + h*DHC + c] = acc[r]/sr;
  }
}

// ---------- FFN v6: R17 + part[] padded to 17 (was 8-way read / 4-way write bank conflict) ----------
__global__ __launch_bounds__(256) void k_ffn(
  const float* __restrict__ xp, const float* __restrict__ ctxb,
  const float* __restrict__ g2, const float* __restrict__ b2v,
  const _Float16* __restrict__ W1s, const float* __restrict__ bb1,
  const _Float16* __restrict__ W2s, const float* __restrict__ bb2,
  float* __restrict__ out)
{
  __shared__ float    hrow[8][DOUTC];
  __shared__ _Float16 hn[16][136];
  __shared__ float    part[4][8][16][17];    // pad 17: stride 68 floats -> conflict-free

  int tid = threadIdx.x, w = tid>>6, lane = tid&63;
  int c = lane&15, g = lane>>4;
  int n0 = blockIdx.x * 8;

#pragma unroll
  for (int i=tid;i<272;i+=256){
    h4 z = {(_Float16)0.f,(_Float16)0.f,(_Float16)0.f,(_Float16)0.f};
    ((h4*)hn)[272+i] = z;
  }

  float ga=g2[lane], gb=g2[lane+64], ba=b2v[lane], bbx=b2v[lane+64];
#pragma unroll
  for (int rr=0;rr<2;++rr){
    int r = w + rr*4;
    size_t gi = (size_t)(n0+r)*DOUTC + lane;
    float a  = xp[gi]    + ctxb[gi];
    float cc = xp[gi+64] + ctxb[gi+64];
    hrow[r][lane] = a; hrow[r][lane+64] = cc;
    float s = wsum(a+cc);
    float q = wsum(a*a+cc*cc);
    float mean = s*(1.f/DOUTC);
    float var  = q*(1.f/DOUTC) - mean*mean;
    float rstd = rsqrtf(var + 1e-5f);
    hn[r][lane]    = (_Float16)((a -mean)*rstd*ga + ba);
    hn[r][lane+64] = (_Float16)((cc-mean)*rstd*gb + bbx);
  }
  __syncthreads();

  h4 hidB[4];
#pragma unroll
  for (int t=0;t<4;++t){
    int ht = 4*w + t;
    float4 bi = *(const float4*)(bb1 + 16*ht + 4*g);
    f32x4 D1; D1[0]=bi.x; D1[1]=bi.y; D1[2]=bi.z; D1[3]=bi.w;
#pragma unroll
    for (int kt=0;kt<8;++kt){
      h4 f = *(const h4*)(W1s + (size_t)((ht*8+kt)*64 + lane)*4);
      h4 hb = *(const h4*)&hn[c][16*kt + 4*g];
      D1 = __builtin_amdgcn_mfma_f32_16x16x16f16(f, hb, D1, 0,0,0);
    }
#pragma unroll
    for (int r=0;r<4;++r) hidB[t][r] = (_Float16)fmaxf(D1[r], 0.f);
  }

#pragma unroll
  for (int ot=0;ot<8;++ot){
    f32x4 d2 = {0.f,0.f,0.f,0.f};
#pragma unroll
    for (int t=0;t<4;++t){
      h4 f = *(const h4*)(W2s + (size_t)((ot*16 + 4*w + t)*64 + lane)*4);
      d2 = __builtin_amdgcn_mfma_f32_16x16x16f16(f, hidB[t], d2, 0,0,0);
    }
#pragma unroll
    for (int r=0;r<4;++r) part[w][ot][4*g+r][c] = d2[r];
  }
  __syncthreads();

#pragma unroll
  for (int i=tid;i<1024;i+=256){
    int n = i>>7, col = i&127;
    int ot = col>>4, m = col&15;
    float v = part[0][ot][m][n] + part[1][ot][m][n]
            + part[2][ot][m][n] + part[3][ot][m][n];
    out[(size_t)(n0+n)*DOUTC + col] = hrow[n][col] + v + bb2[col];
  }
}

extern "C" void kernel_launch(void* const* d_in, const int* in_sizes, int n_in,
                              void* d_out, int out_size, void* d_ws, size_t ws_size,
                              hipStream_t stream)
{
  const float* x     = (const float*)d_in[0];
  const int*   adj   = (const int*)  d_in[1];
  const float* ea    = (const float*)d_in[2];
  const float* ln1_g = (const float*)d_in[3];
  const float* ln1_b = (const float*)d_in[4];
  const float* Wp    = (const float*)d_in[5];
  const float* bp    = (const float*)d_in[6];
  const float* eln_g = (const float*)d_in[7];
  const float* eln_b = (const float*)d_in[8];
  const float* We1   = (const float*)d_in[9];
  const float* be1   = (const float*)d_in[10];
  const float* We2   = (const float*)d_in[11];
  const float* be2   = (const float*)d_in[12];
  const float* Wq    = (const float*)d_in[13];
  const float* Wk    = (const float*)d_in[14];
  const float* Wv    = (const float*)d_in[15];
  const float* ffW1  = (const float*)d_in[16];
  const float* ffb1  = (const float*)d_in[17];
  const float* ffW2  = (const float*)d_in[18];
  const float* ffb2  = (const float*)d_in[19];
  const float* ln2_g = (const float*)d_in[20];
  const float* ln2_b = (const float*)d_in[21];
  float* out = (float*)d_out;

  char* ws = (char*)d_ws;
  float*    xp  = (float*)(ws);                       // 2MB (f32)
  float*    ctx = (float*)(ws + ((size_t)2<<20));     // 2MB
  _Float16* Qh  = (_Float16*)(ws + ((size_t)4<<20));  // 1MB
  _Float16* Kh  = (_Float16*)(ws + ((size_t)5<<20));  // 1MB
  _Float16* Vh  = (_Float16*)(ws + ((size_t)6<<20));  // 1MB
  _Float16* ebf = (_Float16*)(ws + ((size_t)7<<20));  // 32MB [B,H,N,N] f16
  char* wsw = ws + ((size_t)39<<20);                  // swizzled weights (258KB)
  _Float16* W1s = (_Float16*)(wsw);                   // 64KB
  _Float16* W2s = (_Float16*)(wsw + 65536);           // 64KB
  _Float16* Wps = (_Float16*)(wsw + 131072);          // 32KB
  _Float16* Wqs = (_Float16*)(wsw + 163840);          // 32KB
  _Float16* Wks = (_Float16*)(wsw + 196608);          // 32KB
  _Float16* Wvs = (_Float16*)(wsw + 229376);          // 32KB
  _Float16* Wes = (_Float16*)(wsw + 262144);          // 2KB

  k_prep<<<516, 256, 0, stream>>>(Wp, Wq, Wk, Wv, ffW1, ffW2, We1, We2,
                                  Wps, Wqs, Wks, Wvs, W1s, W2s, Wes);
  k_proj<<<(BB*NN)/16, 256, 0, stream>>>(x, ln1_g, ln1_b, Wps, bp, Wqs, Wks, Wvs, xp, Qh, Kh, Vh);
  k_edge<<<BB*NN, 256, 0, stream>>>(ea, adj, eln_g, eln_b, Wes, be1, be2, ebf);
  k_attn<<<BB*HHC*8, 256, 0, stream>>>(Qh, Kh, Vh, ebf, ctx);
  k_ffn<<<(BB*NN)/8, 256, 0, stream>>>(xp, ctx, ln2_g, ln2_b, W1s, ffb1, W2s, ffb2, out);
}